// Round 1
// baseline (1057.046 us; speedup 1.0000x reference)
//
#include <hip/hip_runtime.h>
#include <cstddef>

// ---------------------------------------------------------------------------
// Problem constants: B=16, N=512, D=256, H=8, DH=16, INNER=128, SCALE=0.25
// ---------------------------------------------------------------------------

// ---------------- generic fp32 GEMM: C[M,N] = A[M,K] @ B[K,N] (+bias) ------
template<bool BIAS>
__global__ __launch_bounds__(256) void gemm_kernel(
    const float* __restrict__ A, const float* __restrict__ Bm,
    const float* __restrict__ bias, float* __restrict__ C,
    int M, int N, int K) {
  __shared__ float As[16][68];   // [k][m], padded: read as float4, ~2-way max
  __shared__ float Bs[16][64];   // [k][n]
  const int t  = threadIdx.x;
  const int bm = blockIdx.y << 6, bn = blockIdx.x << 6;
  const int tr = t >> 4, tc = t & 15;
  float acc[4][4];
#pragma unroll
  for (int i = 0; i < 4; ++i)
#pragma unroll
    for (int j = 0; j < 4; ++j) acc[i][j] = 0.f;

  for (int k0 = 0; k0 < K; k0 += 16) {
#pragma unroll
    for (int l = 0; l < 4; ++l) {
      int idx = t + (l << 8);
      int m  = idx >> 4, kk = idx & 15;
      As[kk][m] = A[(size_t)(bm + m) * K + k0 + kk];
      int kb = idx >> 6, n = idx & 63;
      Bs[kb][n] = Bm[(size_t)(k0 + kb) * N + bn + n];
    }
    __syncthreads();
#pragma unroll
    for (int kk = 0; kk < 16; ++kk) {
      float4 av = *(const float4*)&As[kk][tr << 2];
      float4 bv = *(const float4*)&Bs[kk][tc << 2];
      float a[4] = {av.x, av.y, av.z, av.w};
      float b[4] = {bv.x, bv.y, bv.z, bv.w};
#pragma unroll
      for (int i = 0; i < 4; ++i)
#pragma unroll
        for (int j = 0; j < 4; ++j) acc[i][j] += a[i] * b[j];
    }
    __syncthreads();
  }
#pragma unroll
  for (int i = 0; i < 4; ++i) {
    int row = bm + (tr << 2) + i;
#pragma unroll
    for (int j = 0; j < 4; ++j) {
      int col = bn + (tc << 2) + j;
      float v = acc[i][j];
      if (BIAS) v += bias[col];
      C[(size_t)row * N + col] = v;
    }
  }
}

// ---------------- fused attention (energy -> share, softmax, @V) -----------
// qkv layout: [B][NTOK][384], q = cols 0..127, k = 128..255, v = 256..383,
// head h occupies 16 cols at h*16 within each section.
// Block: 256 threads (4 waves), handles one (b,h) x 32 query rows.
template<int NTOK>
__global__ __launch_bounds__(256) void attn_kernel(
    const float* __restrict__ qkv, float* __restrict__ share,
    float* __restrict__ out) {
  extern __shared__ float lds[];
  float* Kt = lds;               // [16][NTOK]  (d-major: conflict-free reads)
  float* Vt = lds + 16 * NTOK;   // [16][NTOK]
  constexpr int JPER = NTOK / 64;
  const int blocksPerBH = NTOK / 32;
  const int bh = blockIdx.x / blocksPerBH;
  const int rowBlock = blockIdx.x % blocksPerBH;
  const int b = bh >> 3, h = bh & 7;
  const int wave = threadIdx.x >> 6, lane = threadIdx.x & 63;
  const float* qkvb = qkv + (size_t)b * NTOK * 384;

  // stage K,V into LDS: one token per thread -> [d][j] writes, consecutive j
  for (int j = threadIdx.x; j < NTOK; j += 256) {
    const float* kp = qkvb + (size_t)j * 384 + 128 + h * 16;
    const float* vp = qkvb + (size_t)j * 384 + 256 + h * 16;
#pragma unroll
    for (int d = 0; d < 16; ++d) {
      Kt[d * NTOK + j] = kp[d];
      Vt[d * NTOK + j] = vp[d];
    }
  }
  __syncthreads();

  float* shbase = share + (size_t)bh * NTOK * NTOK;
  for (int r = 0; r < 8; ++r) {
    const int i = (rowBlock << 5) + (r << 2) + wave;  // query row
    float q[16];
    const float* qp = qkvb + (size_t)i * 384 + h * 16;
#pragma unroll
    for (int d = 0; d < 16; ++d) q[d] = qp[d];

    float e[JPER];
    float m = -1e30f;
#pragma unroll
    for (int jj = 0; jj < JPER; ++jj) {
      int j = (jj << 6) + lane;
      float s = 0.f;
#pragma unroll
      for (int d = 0; d < 16; ++d) s += q[d] * Kt[d * NTOK + j];
      s *= 0.25f;                 // SCALE = DH^-0.5
      e[jj] = s;
      m = fmaxf(m, s);
      shbase[(size_t)i * NTOK + j] = s;   // raw energy -> share output
    }
#pragma unroll
    for (int off = 32; off; off >>= 1) m = fmaxf(m, __shfl_xor(m, off));
    float sum = 0.f;
#pragma unroll
    for (int jj = 0; jj < JPER; ++jj) { e[jj] = expf(e[jj] - m); sum += e[jj]; }
#pragma unroll
    for (int off = 32; off; off >>= 1) sum += __shfl_xor(sum, off);
    float inv = 1.f / sum;

    float acc[16];
#pragma unroll
    for (int d = 0; d < 16; ++d) acc[d] = 0.f;
#pragma unroll
    for (int jj = 0; jj < JPER; ++jj) {
      int j = (jj << 6) + lane;
      float p = e[jj];
#pragma unroll
      for (int d = 0; d < 16; ++d) acc[d] += p * Vt[d * NTOK + j];
    }
#pragma unroll
    for (int d = 0; d < 16; ++d) {
#pragma unroll
      for (int off = 32; off; off >>= 1) acc[d] += __shfl_xor(acc[d], off);
    }
    if (lane < 16)
      out[((size_t)b * NTOK + i) * 128 + h * 16 + lane] = acc[lane] * inv;
  }
}

// ---------------- y = LayerNorm(a + res) over last dim D (block = D) -------
__global__ void add_ln_kernel(const float* __restrict__ a,
                              const float* __restrict__ res,
                              const float* __restrict__ g,
                              const float* __restrict__ beta,
                              float* __restrict__ y, int D) {
  int row = blockIdx.x;
  int t = threadIdx.x;
  size_t base = (size_t)row * D;
  float x = a[base + t] + res[base + t];
  float s = x, s2 = x * x;
#pragma unroll
  for (int off = 32; off; off >>= 1) {
    s  += __shfl_xor(s, off);
    s2 += __shfl_xor(s2, off);
  }
  __shared__ float ws1[8], ws2[8];
  int wave = t >> 6, lane = t & 63;
  int nw = blockDim.x >> 6;
  if (lane == 0) { ws1[wave] = s; ws2[wave] = s2; }
  __syncthreads();
  if (t == 0) {
    float ts = 0.f, ts2 = 0.f;
    for (int w = 0; w < nw; ++w) { ts += ws1[w]; ts2 += ws2[w]; }
    ws1[0] = ts; ws2[0] = ts2;
  }
  __syncthreads();
  float mean = ws1[0] / D;
  float var  = ws2[0] / D - mean * mean;
  float rstd = rsqrtf(var + 1e-5f);
  y[base + t] = (x - mean) * rstd * g[t] + beta[t];
}

// ---------------- GEGLU: u = a * gelu_exact(g),  h=[rows][2*halfN] ---------
__global__ __launch_bounds__(256) void geglu_kernel(
    const float* __restrict__ h, float* __restrict__ u,
    int halfN, size_t total) {
  size_t i = (size_t)blockIdx.x * 256 + threadIdx.x;
  if (i >= total) return;
  size_t row = i / (size_t)halfN;
  int c = (int)(i - row * (size_t)halfN);
  float a = h[row * (size_t)(halfN * 2) + c];
  float g = h[row * (size_t)(halfN * 2) + halfN + c];
  float ge = 0.5f * g * (1.f + erff(g * 0.70710678118654752f));  // exact GELU
  u[i] = a * ge;
}

// ---------------- batched transpose: in[B][R][C] -> out[B][C][R] -----------
__global__ void transpose_kernel(const float* __restrict__ in,
                                 float* __restrict__ out, int R, int C) {
  __shared__ float tile[32][33];
  int b = blockIdx.z;
  int r0 = blockIdx.y << 5, c0 = blockIdx.x << 5;
  const float* inb = in + (size_t)b * R * C;
  float* outb = out + (size_t)b * R * C;
  int tx = threadIdx.x, ty = threadIdx.y;   // block (32,8)
#pragma unroll
  for (int dy = 0; dy < 32; dy += 8)
    tile[ty + dy][tx] = inb[(size_t)(r0 + ty + dy) * C + c0 + tx];
  __syncthreads();
#pragma unroll
  for (int dy = 0; dy < 32; dy += 8)
    outb[(size_t)(c0 + ty + dy) * R + r0 + tx] = tile[tx][ty + dy];
}

// ---------------------------------------------------------------------------
extern "C" void kernel_launch(void* const* d_in, const int* in_sizes, int n_in,
                              void* d_out, int out_size, void* d_ws, size_t ws_size,
                              hipStream_t stream) {
  (void)in_sizes; (void)n_in; (void)out_size; (void)ws_size;
  const float* x0    = (const float*)d_in[0];
  const float* wqkv1 = (const float*)d_in[1];
  const float* wo1   = (const float*)d_in[2];
  const float* bo1   = (const float*)d_in[3];
  const float* ff1w1 = (const float*)d_in[4];
  const float* ff1b1 = (const float*)d_in[5];
  const float* ff1w2 = (const float*)d_in[6];
  const float* ff1b2 = (const float*)d_in[7];
  const float* wqkv2 = (const float*)d_in[8];
  const float* wo2   = (const float*)d_in[9];
  const float* bo2   = (const float*)d_in[10];
  const float* ff2w1 = (const float*)d_in[11];
  const float* ff2b1 = (const float*)d_in[12];
  const float* ff2w2 = (const float*)d_in[13];
  const float* ff2b2 = (const float*)d_in[14];
  const float* ln1g  = (const float*)d_in[15];
  const float* ln1b  = (const float*)d_in[16];
  const float* ln2g  = (const float*)d_in[17];
  const float* ln2b  = (const float*)d_in[18];
  const float* ln3g  = (const float*)d_in[19];
  const float* ln3b  = (const float*)d_in[20];
  const float* ln4g  = (const float*)d_in[21];
  const float* ln4b  = (const float*)d_in[22];

  // outputs: x [16,512,256] | share [16,8,512,512] | share2 [16,8,256,256]
  float* out_x  = (float*)d_out;
  float* share1 = out_x + (size_t)2097152;
  float* share2 = share1 + (size_t)33554432;

  // workspace layout (floats); total 35,651,584 floats = 142.6 MB
  float* ws   = (float*)d_ws;
  float* xa   = ws;               // 2,097,152
  float* xb   = xa + 2097152;     // 2,097,152
  float* qkv  = xb + 2097152;     // 3,145,728
  float* attn = qkv + 3145728;    // 1,048,576
  float* proj = attn + 1048576;   // 2,097,152
  float* hbuf = proj + 2097152;   // 16,777,216
  float* ubuf = hbuf + 16777216;  // 8,388,608

  // allow 64 KiB dynamic LDS for stage-1 attention (belt & braces)
  (void)hipFuncSetAttribute(reinterpret_cast<const void*>(&attn_kernel<512>),
                            hipFuncAttributeMaxDynamicSharedMemorySize, 65536);

  // ---------------- stage 1 (tokens=512, feat=256) ----------------
  // qkv1 = x @ wqkv1                       [8192,256]@[256,384]
  gemm_kernel<false><<<dim3(6, 128), 256, 0, stream>>>(x0, wqkv1, nullptr, qkv, 8192, 384, 256);
  // attention: energy->share1, softmax, @V -> attn [16,512,128]
  attn_kernel<512><<<2048, 256, 65536, stream>>>(qkv, share1, attn);
  // proj = attn @ wo1 + bo1                [8192,128]@[128,256]
  gemm_kernel<true><<<dim3(4, 128), 256, 0, stream>>>(attn, wo1, bo1, proj, 8192, 256, 128);
  // xa = LN1(proj + x0)
  add_ln_kernel<<<8192, 256, 0, stream>>>(proj, x0, ln1g, ln1b, xa, 256);
  // h = xa @ ff1_w1 + b                    [8192,256]@[256,2048]
  gemm_kernel<true><<<dim3(32, 128), 256, 0, stream>>>(xa, ff1w1, ff1b1, hbuf, 8192, 2048, 256);
  // u = a * gelu(g)
  geglu_kernel<<<32768, 256, 0, stream>>>(hbuf, ubuf, 1024, (size_t)8388608);
  // proj = u @ ff1_w2 + b                  [8192,1024]@[1024,256]
  gemm_kernel<true><<<dim3(4, 128), 256, 0, stream>>>(ubuf, ff1w2, ff1b2, proj, 8192, 256, 1024);
  // xb = LN2(proj + xa)
  add_ln_kernel<<<8192, 256, 0, stream>>>(proj, xa, ln2g, ln2b, xb, 256);

  // ---------------- transpose to [B, 256, 512] ----------------
  transpose_kernel<<<dim3(8, 16, 16), dim3(32, 8), 0, stream>>>(xb, xa, 512, 256);

  // ---------------- stage 2 (tokens=256, feat=512) ----------------
  // qkv2 = xt @ wqkv2                      [4096,512]@[512,384]
  gemm_kernel<false><<<dim3(6, 64), 256, 0, stream>>>(xa, wqkv2, nullptr, qkv, 4096, 384, 512);
  // attention: energy->share2, softmax, @V -> attn [16,256,128]
  attn_kernel<256><<<1024, 256, 32768, stream>>>(qkv, share2, attn);
  // proj = attn @ wo2 + bo2                [4096,128]@[128,512]
  gemm_kernel<true><<<dim3(8, 64), 256, 0, stream>>>(attn, wo2, bo2, proj, 4096, 512, 128);
  // xb = LN3(proj + xt)
  add_ln_kernel<<<4096, 512, 0, stream>>>(proj, xa, ln3g, ln3b, xb, 512);
  // h = xb @ ff2_w1 + b                    [4096,512]@[512,4096]
  gemm_kernel<true><<<dim3(64, 64), 256, 0, stream>>>(xb, ff2w1, ff2b1, hbuf, 4096, 4096, 512);
  // u = a * gelu(g)
  geglu_kernel<<<32768, 256, 0, stream>>>(hbuf, ubuf, 2048, (size_t)8388608);
  // proj = u @ ff2_w2 + b                  [4096,2048]@[2048,512]
  gemm_kernel<true><<<dim3(8, 64), 256, 0, stream>>>(ubuf, ff2w2, ff2b2, proj, 4096, 512, 2048);
  // xa = LN4(proj + xb)
  add_ln_kernel<<<4096, 512, 0, stream>>>(proj, xb, ln4g, ln4b, xa, 512);

  // ---------------- transpose back to [B, 512, 256] -> out ----------------
  transpose_kernel<<<dim3(16, 8, 16), dim3(32, 8), 0, stream>>>(xa, out_x, 256, 512);
}

// Round 2
// 319.938 us; speedup vs baseline: 3.3039x; 3.3039x over previous
//
#include <hip/hip_runtime.h>
#include <cstddef>

// ---------------------------------------------------------------------------
// B=16, N=512, D=256, H=8, DH=16, INNER=128, SCALE=0.25
// Strategy: bf16 MFMA for all GEMMs + MFMA attention; fp32 residual spine.
// ---------------------------------------------------------------------------

typedef __attribute__((ext_vector_type(8))) short short8;
typedef __attribute__((ext_vector_type(4))) float f32x4;
typedef unsigned short u16t;

__device__ __forceinline__ u16t f2b(float f) {           // fp32 -> bf16 (RNE)
  union { float f; unsigned u; } x; x.f = f;
  unsigned r = (x.u + 0x7fffu + ((x.u >> 16) & 1u)) >> 16;
  return (u16t)r;
}
__device__ __forceinline__ float b2f(u16t v) {
  union { unsigned u; float f; } x; x.u = ((unsigned)v) << 16;
  return x.f;
}

// ---------------- bf16 MFMA GEMM: C[M,N] = A[M,K] @ BT[N,K]^T (+bias) ------
// 128x128 tile, BK=32, 256 threads = 4 waves, each wave a 64x64 subtile.
template<bool BIAS, bool BF16OUT>
__global__ __launch_bounds__(256) void mgemm(
    const u16t* __restrict__ A, const u16t* __restrict__ BT,
    const float* __restrict__ bias, void* __restrict__ C,
    int M, int N, int K) {
  __shared__ u16t Al[128][40];   // rows padded 32->40 bf16 (80B, 16B-aligned)
  __shared__ u16t Bl[128][40];
  const int t = threadIdx.x;
  const int lane = t & 63, wid = t >> 6;
  const int wr = wid >> 1, wc = wid & 1;
  const int lr = lane & 15, lq = lane >> 4;
  const int bm = blockIdx.y << 7, bn = blockIdx.x << 7;
  const int srow = t >> 1, skoff = (t & 1) << 4;   // stage: 16 bf16 per thread x2
  f32x4 acc[4][4];
#pragma unroll
  for (int m = 0; m < 4; ++m)
#pragma unroll
    for (int n = 0; n < 4; ++n) acc[m][n] = (f32x4){0.f, 0.f, 0.f, 0.f};

  for (int k0 = 0; k0 < K; k0 += 32) {
    short8 av0 = *(const short8*)&A[(size_t)(bm + srow) * K + k0 + skoff];
    short8 av1 = *(const short8*)&A[(size_t)(bm + srow) * K + k0 + skoff + 8];
    short8 bv0 = *(const short8*)&BT[(size_t)(bn + srow) * K + k0 + skoff];
    short8 bv1 = *(const short8*)&BT[(size_t)(bn + srow) * K + k0 + skoff + 8];
    __syncthreads();
    *(short8*)&Al[srow][skoff]     = av0;
    *(short8*)&Al[srow][skoff + 8] = av1;
    *(short8*)&Bl[srow][skoff]     = bv0;
    *(short8*)&Bl[srow][skoff + 8] = bv1;
    __syncthreads();
    short8 af[4], bf[4];
#pragma unroll
    for (int m = 0; m < 4; ++m)
      af[m] = *(const short8*)&Al[wr * 64 + m * 16 + lr][lq * 8];
#pragma unroll
    for (int n = 0; n < 4; ++n)
      bf[n] = *(const short8*)&Bl[wc * 64 + n * 16 + lr][lq * 8];
#pragma unroll
    for (int m = 0; m < 4; ++m)
#pragma unroll
      for (int n = 0; n < 4; ++n)
        acc[m][n] = __builtin_amdgcn_mfma_f32_16x16x32_bf16(af[m], bf[n], acc[m][n], 0, 0, 0);
  }
  // epilogue: C/D layout col=lane&15, row=(lane>>4)*4+i  [m89-verified]
#pragma unroll
  for (int n = 0; n < 4; ++n) {
    const int col = bn + wc * 64 + n * 16 + lr;
    const float bv = BIAS ? bias[col] : 0.f;
#pragma unroll
    for (int m = 0; m < 4; ++m) {
#pragma unroll
      for (int i = 0; i < 4; ++i) {
        const int row = bm + wr * 64 + m * 16 + lq * 4 + i;
        const float v = acc[m][n][i] + bv;
        if (BF16OUT) ((u16t*)C)[(size_t)row * N + col] = f2b(v);
        else         ((float*)C)[(size_t)row * N + col] = v;
      }
    }
  }
}

// ---------------- MFMA attention ------------------------------------------
// qkv bf16 [B][NTOK][384]; per block: one (b,h), 64 query rows (16/wave).
// Energy via mfma(Q, K^T) (K-frags straight from global/L1), raw energy ->
// share; single-pass softmax (|e| small: no max needed); P bounced through
// per-wave LDS tile into A-frag layout; PV via mfma(P, V) with V transposed
// in LDS.
template<int NTOK>
__global__ __launch_bounds__(256) void attn_mfma(
    const u16t* __restrict__ qkv, float* __restrict__ share,
    u16t* __restrict__ outb) {
  __shared__ u16t VT[16][NTOK + 40];   // V^T, stride 20 dwords -> phase-clean
  __shared__ u16t PB[4][16][40];       // per-wave P bounce tile
  const int t = threadIdx.x, lane = t & 63, wv = t >> 6;
  const int lr = lane & 15, lq = lane >> 4;
  const int bpb = NTOK / 64;
  const int bh = blockIdx.x / bpb, rg = blockIdx.x % bpb;
  const int b = bh >> 3, h = bh & 7;
  const u16t* qkvb = qkv + (size_t)b * NTOK * 384;

  // stage V transposed into LDS
  for (int tok = t; tok < NTOK; tok += 256) {
    const u16t* vp = qkvb + (size_t)tok * 384 + 256 + h * 16;
    short8 v0 = *(const short8*)vp;
    short8 v1 = *(const short8*)(vp + 8);
#pragma unroll
    for (int d = 0; d < 8; ++d) {
      VT[d][tok]     = (u16t)v0[d];
      VT[d + 8][tok] = (u16t)v1[d];
    }
  }
  __syncthreads();

  const int i0 = rg * 64 + wv * 16;    // this wave's 16 query rows
  short8 qf = {0, 0, 0, 0, 0, 0, 0, 0};   // A-frag: row=lr, k=lq*8+j (k>=16 zero)
  if (lq < 2)
    qf = *(const short8*)(qkvb + (size_t)(i0 + lr) * 384 + h * 16 + lq * 8);

  f32x4 oacc = {0.f, 0.f, 0.f, 0.f};
  f32x4 sacc = {0.f, 0.f, 0.f, 0.f};
  const f32x4 zero = {0.f, 0.f, 0.f, 0.f};
  float* shb = share + (size_t)bh * NTOK * NTOK;

  for (int t0 = 0; t0 < NTOK; t0 += 32) {
#pragma unroll
    for (int s2 = 0; s2 < 2; ++s2) {
      short8 kf = {0, 0, 0, 0, 0, 0, 0, 0};  // B-frag: col=tok=lr, k=dh=lq*8+j
      if (lq < 2)
        kf = *(const short8*)(qkvb + (size_t)(t0 + s2 * 16 + lr) * 384 + 128 + h * 16 + lq * 8);
      f32x4 e = __builtin_amdgcn_mfma_f32_16x16x32_bf16(qf, kf, zero, 0, 0, 0);
#pragma unroll
      for (int i = 0; i < 4; ++i) {
        const float ev = e[i] * 0.25f;                       // SCALE
        shb[(size_t)(i0 + lq * 4 + i) * NTOK + t0 + s2 * 16 + lr] = ev;
        const float p = __expf(ev);
        sacc[i] += p;
        PB[wv][lq * 4 + i][s2 * 16 + lr] = f2b(p);
      }
    }
    __syncthreads();   // PB writes -> cross-lane reads
    short8 pa = *(const short8*)&PB[wv][lr][lq * 8];         // A-frag of P
    short8 vf = *(const short8*)&VT[lr][t0 + lq * 8];        // B-frag of V
    oacc = __builtin_amdgcn_mfma_f32_16x16x32_bf16(pa, vf, oacc, 0, 0, 0);
    __syncthreads();   // protect PB before next tile's writes
  }
  // row sums: reduce over the 16 col-lanes of each group
#pragma unroll
  for (int i = 0; i < 4; ++i) {
    float s = sacc[i];
    s += __shfl_xor(s, 1); s += __shfl_xor(s, 2);
    s += __shfl_xor(s, 4); s += __shfl_xor(s, 8);
    sacc[i] = s;
  }
#pragma unroll
  for (int i = 0; i < 4; ++i) {
    const float o = oacc[i] / sacc[i];
    outb[((size_t)(b * NTOK) + i0 + lq * 4 + i) * 128 + h * 16 + lr] = f2b(o);
  }
}

// ---------------- y = LayerNorm(a + res); optional bf16 twin output --------
template<bool BF16OUT>
__global__ void add_ln(const float* __restrict__ a, const float* __restrict__ res,
                       const float* __restrict__ g, const float* __restrict__ be,
                       float* __restrict__ y32, u16t* __restrict__ y16, int D) {
  const int row = blockIdx.x, t = threadIdx.x;
  const size_t base = (size_t)row * D;
  const float x = a[base + t] + res[base + t];
  float s = x, s2 = x * x;
#pragma unroll
  for (int off = 32; off; off >>= 1) {
    s  += __shfl_xor(s, off);
    s2 += __shfl_xor(s2, off);
  }
  __shared__ float ws1[8], ws2[8];
  const int wave = t >> 6, lane = t & 63, nw = blockDim.x >> 6;
  if (lane == 0) { ws1[wave] = s; ws2[wave] = s2; }
  __syncthreads();
  if (t == 0) {
    float ts = 0.f, ts2 = 0.f;
    for (int w = 0; w < nw; ++w) { ts += ws1[w]; ts2 += ws2[w]; }
    ws1[0] = ts; ws2[0] = ts2;
  }
  __syncthreads();
  const float mean = ws1[0] / D;
  const float var  = ws2[0] / D - mean * mean;
  const float rstd = rsqrtf(var + 1e-5f);
  const float y = (x - mean) * rstd * g[t] + be[t];
  y32[base + t] = y;
  if (BF16OUT) y16[base + t] = f2b(y);
}

// ---------------- GEGLU on bf16: u = a * gelu_exact(g) ---------------------
__global__ __launch_bounds__(256) void geglu16(
    const u16t* __restrict__ h, u16t* __restrict__ u, int halfN, int total8) {
  const int i = blockIdx.x * 256 + threadIdx.x;   // index in 8-element units
  if (i >= total8) return;
  const int per = halfN >> 3;
  const int row = i / per, c8 = i - row * per;
  const u16t* ap = h + (size_t)row * (halfN * 2) + c8 * 8;
  short8 av = *(const short8*)ap;
  short8 gv = *(const short8*)(ap + halfN);
  short8 uv;
#pragma unroll
  for (int j = 0; j < 8; ++j) {
    const float a = b2f((u16t)av[j]);
    const float g = b2f((u16t)gv[j]);
    const float ge = 0.5f * g * (1.f + erff(g * 0.70710678118654752f));
    uv[j] = (short)f2b(a * ge);
  }
  *(short8*)(u + (size_t)row * halfN + c8 * 8) = uv;
}

// ---------------- batched transpose [B][R][C]->[B][C][R], opt bf16 twin ----
template<bool BF16OUT>
__global__ void transp(const float* __restrict__ in, float* __restrict__ out32,
                       u16t* __restrict__ out16, int R, int C) {
  __shared__ float tile[32][33];
  const int b = blockIdx.z;
  const int r0 = blockIdx.y << 5, c0 = blockIdx.x << 5;
  const float* inb = in + (size_t)b * R * C;
  const int tx = threadIdx.x, ty = threadIdx.y;   // block (32,8)
#pragma unroll
  for (int dy = 0; dy < 32; dy += 8)
    tile[ty + dy][tx] = inb[(size_t)(r0 + ty + dy) * C + c0 + tx];
  __syncthreads();
#pragma unroll
  for (int dy = 0; dy < 32; dy += 8) {
    const float v = tile[tx][ty + dy];
    const size_t idx = (size_t)b * R * C + (size_t)(c0 + ty + dy) * R + r0 + tx;
    out32[idx] = v;
    if (BF16OUT) out16[idx] = f2b(v);
  }
}

// ---------------- weight convert+transpose: W[K][N] f32 -> WT[N][K] bf16 ---
__global__ void convt(const float* __restrict__ W, u16t* __restrict__ WT,
                      int K, int N) {
  __shared__ float tile[32][33];
  const int k0 = blockIdx.y << 5, n0 = blockIdx.x << 5;
  const int tx = threadIdx.x, ty = threadIdx.y;
#pragma unroll
  for (int dy = 0; dy < 32; dy += 8)
    tile[ty + dy][tx] = W[(size_t)(k0 + ty + dy) * N + n0 + tx];
  __syncthreads();
#pragma unroll
  for (int dy = 0; dy < 32; dy += 8)
    WT[(size_t)(n0 + ty + dy) * K + k0 + tx] = f2b(tile[tx][ty + dy]);
}

// ---------------- linear f32 -> bf16 convert -------------------------------
__global__ __launch_bounds__(256) void conv8(const float* __restrict__ in,
                                             u16t* __restrict__ out, int total8) {
  const int i = blockIdx.x * 256 + threadIdx.x;
  if (i >= total8) return;
  const float* p = in + (size_t)i * 8;
  short8 v;
#pragma unroll
  for (int j = 0; j < 8; ++j) v[j] = (short)f2b(p[j]);
  *(short8*)(out + (size_t)i * 8) = v;
}

// ---------------------------------------------------------------------------
extern "C" void kernel_launch(void* const* d_in, const int* in_sizes, int n_in,
                              void* d_out, int out_size, void* d_ws, size_t ws_size,
                              hipStream_t stream) {
  (void)in_sizes; (void)n_in; (void)out_size; (void)ws_size;
  const float* x0    = (const float*)d_in[0];
  const float* wqkv1 = (const float*)d_in[1];
  const float* wo1   = (const float*)d_in[2];
  const float* bo1   = (const float*)d_in[3];
  const float* ff1w1 = (const float*)d_in[4];
  const float* ff1b1 = (const float*)d_in[5];
  const float* ff1w2 = (const float*)d_in[6];
  const float* ff1b2 = (const float*)d_in[7];
  const float* wqkv2 = (const float*)d_in[8];
  const float* wo2   = (const float*)d_in[9];
  const float* bo2   = (const float*)d_in[10];
  const float* ff2w1 = (const float*)d_in[11];
  const float* ff2b1 = (const float*)d_in[12];
  const float* ff2w2 = (const float*)d_in[13];
  const float* ff2b2 = (const float*)d_in[14];
  const float* ln1g  = (const float*)d_in[15];
  const float* ln1b  = (const float*)d_in[16];
  const float* ln2g  = (const float*)d_in[17];
  const float* ln2b  = (const float*)d_in[18];
  const float* ln3g  = (const float*)d_in[19];
  const float* ln3b  = (const float*)d_in[20];
  const float* ln4g  = (const float*)d_in[21];
  const float* ln4b  = (const float*)d_in[22];

  // outputs: x [16,512,256] | share [16,8,512,512] | share2 [16,8,256,256]
  float* out_x  = (float*)d_out;
  float* share1 = out_x + (size_t)2097152;
  float* share2 = share1 + (size_t)33554432;

  // workspace carve-up (256B aligned), total ~134.5 MB
  size_t off = 0;
  auto carve = [&](size_t bytes) -> void* {
    void* p = (char*)d_ws + off;
    off += (bytes + 255) & ~(size_t)255;
    return p;
  };
  u16t*  x16    = (u16t*)carve((size_t)8192 * 256 * 2);
  u16t*  qkv16  = (u16t*)carve((size_t)8192 * 384 * 2);
  u16t*  attn16 = (u16t*)carve((size_t)8192 * 128 * 2);
  float* proj   = (float*)carve((size_t)8192 * 256 * 4);
  float* xa32   = (float*)carve((size_t)8192 * 256 * 4);
  u16t*  xa16   = (u16t*)carve((size_t)8192 * 256 * 2);
  float* xb32   = (float*)carve((size_t)8192 * 256 * 4);
  float* xt32   = (float*)carve((size_t)8192 * 256 * 4);
  u16t*  xt16   = (u16t*)carve((size_t)8192 * 256 * 2);
  float* xc32   = (float*)carve((size_t)8192 * 256 * 4);
  u16t*  xc16   = (u16t*)carve((size_t)8192 * 256 * 2);
  float* xd32   = (float*)carve((size_t)8192 * 256 * 4);
  u16t*  hbuf   = (u16t*)carve((size_t)8192 * 2048 * 2);
  u16t*  ubuf   = (u16t*)carve((size_t)8192 * 1024 * 2);
  u16t*  wtqkv1 = (u16t*)carve((size_t)256 * 384 * 2);
  u16t*  wtwo1  = (u16t*)carve((size_t)128 * 256 * 2);
  u16t*  wtff1a = (u16t*)carve((size_t)256 * 2048 * 2);
  u16t*  wtff1b = (u16t*)carve((size_t)1024 * 256 * 2);
  u16t*  wtqkv2 = (u16t*)carve((size_t)512 * 384 * 2);
  u16t*  wtwo2  = (u16t*)carve((size_t)128 * 512 * 2);
  u16t*  wtff2a = (u16t*)carve((size_t)512 * 4096 * 2);
  u16t*  wtff2b = (u16t*)carve((size_t)2048 * 512 * 2);

  const dim3 tb(32, 8);
  // ---- pre-pass: converts ----
  conv8<<<1024, 256, 0, stream>>>(x0, x16, 262144);
  convt<<<dim3(12, 8),   tb, 0, stream>>>(wqkv1, wtqkv1, 256, 384);
  convt<<<dim3(8, 4),    tb, 0, stream>>>(wo1,   wtwo1,  128, 256);
  convt<<<dim3(64, 8),   tb, 0, stream>>>(ff1w1, wtff1a, 256, 2048);
  convt<<<dim3(8, 32),   tb, 0, stream>>>(ff1w2, wtff1b, 1024, 256);
  convt<<<dim3(12, 16),  tb, 0, stream>>>(wqkv2, wtqkv2, 512, 384);
  convt<<<dim3(16, 4),   tb, 0, stream>>>(wo2,   wtwo2,  128, 512);
  convt<<<dim3(128, 16), tb, 0, stream>>>(ff2w1, wtff2a, 512, 4096);
  convt<<<dim3(16, 64),  tb, 0, stream>>>(ff2w2, wtff2b, 2048, 512);

  // ---- stage 1 (tokens=512, feat=256) ----
  mgemm<false, true><<<dim3(3, 64), 256, 0, stream>>>(x16, wtqkv1, nullptr, qkv16, 8192, 384, 256);
  attn_mfma<512><<<1024, 256, 0, stream>>>(qkv16, share1, attn16);
  mgemm<true, false><<<dim3(2, 64), 256, 0, stream>>>(attn16, wtwo1, bo1, proj, 8192, 256, 128);
  add_ln<true><<<8192, 256, 0, stream>>>(proj, x0, ln1g, ln1b, xa32, xa16, 256);
  mgemm<true, true><<<dim3(16, 64), 256, 0, stream>>>(xa16, wtff1a, ff1b1, hbuf, 8192, 2048, 256);
  geglu16<<<4096, 256, 0, stream>>>(hbuf, ubuf, 1024, 1048576);
  mgemm<true, false><<<dim3(2, 64), 256, 0, stream>>>(ubuf, wtff1b, ff1b2, proj, 8192, 256, 1024);
  add_ln<false><<<8192, 256, 0, stream>>>(proj, xa32, ln2g, ln2b, xb32, nullptr, 256);

  // ---- transpose to [B,256,512] ----
  transp<true><<<dim3(8, 16, 16), tb, 0, stream>>>(xb32, xt32, xt16, 512, 256);

  // ---- stage 2 (tokens=256, feat=512) ----
  mgemm<false, true><<<dim3(3, 32), 256, 0, stream>>>(xt16, wtqkv2, nullptr, qkv16, 4096, 384, 512);
  attn_mfma<256><<<512, 256, 0, stream>>>(qkv16, share2, attn16);
  mgemm<true, false><<<dim3(4, 32), 256, 0, stream>>>(attn16, wtwo2, bo2, proj, 4096, 512, 128);
  add_ln<true><<<4096, 512, 0, stream>>>(proj, xt32, ln3g, ln3b, xc32, xc16, 512);
  mgemm<true, true><<<dim3(32, 32), 256, 0, stream>>>(xc16, wtff2a, ff2b1, hbuf, 4096, 4096, 512);
  geglu16<<<4096, 256, 0, stream>>>(hbuf, ubuf, 2048, 1048576);
  mgemm<true, false><<<dim3(4, 32), 256, 0, stream>>>(ubuf, wtff2b, ff2b2, proj, 4096, 512, 2048);
  add_ln<false><<<4096, 512, 0, stream>>>(proj, xc32, ln4g, ln4b, xd32, nullptr, 512);

  // ---- transpose back -> out ----
  transp<false><<<dim3(16, 8, 16), tb, 0, stream>>>(xd32, out_x, nullptr, 256, 512);
}

// Round 3
// 230.426 us; speedup vs baseline: 4.5873x; 1.3885x over previous
//
#include <hip/hip_runtime.h>
#include <cstddef>

// ---------------------------------------------------------------------------
// B=16, N=512, D=256, H=8, DH=16, INNER=128, SCALE=0.25
// bf16 MFMA everywhere; global_load_lds staging; fused GEGLU via weight-col
// permutation; fused residual in GEMM epilogue; single prep kernel.
// ---------------------------------------------------------------------------

typedef __attribute__((ext_vector_type(8))) short short8;
typedef __attribute__((ext_vector_type(4))) short bf16x4;
typedef __attribute__((ext_vector_type(4))) float f32x4;
typedef unsigned short u16t;

__device__ __forceinline__ u16t f2b(float f) {           // fp32 -> bf16 (RNE)
  union { float f; unsigned u; } x; x.f = f;
  unsigned r = (x.u + 0x7fffu + ((x.u >> 16) & 1u)) >> 16;
  return (u16t)r;
}
__device__ __forceinline__ float b2f(u16t v) {
  union { unsigned u; float f; } x; x.u = ((unsigned)v) << 16;
  return x.f;
}

__device__ __forceinline__ void gload16(const void* g, void* l) {
  __builtin_amdgcn_global_load_lds(
      (const __attribute__((address_space(1))) void*)g,
      (__attribute__((address_space(3))) void*)l, 16, 0, 0);
}

// GEGLU weight-column permutation: n_new -> n_orig.
// 128-col blocks hold pairs: 16-col chunk s (0..7): even->a, odd->g.
__device__ __forceinline__ int origcol(int n, int halfN) {
  const int nb = n >> 7, s = (n >> 4) & 7, r = n & 15;
  return ((s & 1) ? halfN : 0) + (nb << 6) + ((s >> 1) << 4) + r;
}

// ---------------- bf16 MFMA GEMM, global_load_lds staging ------------------
// C[M,N] = A[M,K] @ BT[N,K]^T. 128xBN tile, BK=32, 256 threads.
// EPI: 0 = bf16 out (+opt bias), 1 = f32 out + bias + residual, 2 = GEGLU.
template<int BN, int EPI>
__global__ __launch_bounds__(256) void mgemm(
    const u16t* __restrict__ A, const u16t* __restrict__ BT,
    const float* __restrict__ bias, const float* __restrict__ res,
    void* __restrict__ C, int M, int N, int K) {
  constexpr int WGC = (BN == 128) ? 2 : 1;      // wave grid cols
  constexpr int WM = (WGC == 2) ? 64 : 32;      // per-wave rows
  constexpr int MR = WM / 16;
  constexpr int NR = 4;                         // per-wave cols = 64
  constexpr int BISS = BN / 64;                 // B gload issues per wave
  __shared__ u16t Al[128 * 32];                 // linear: gload_lds dest
  __shared__ u16t Bl[BN * 32];
  const int t = threadIdx.x, lane = t & 63, wid = t >> 6;
  const int wr = (WGC == 2) ? (wid >> 1) : wid;
  const int wc = (WGC == 2) ? (wid & 1) : 0;
  const int lr = lane & 15, lq = lane >> 4;
  const int bm = blockIdx.y << 7, bn = blockIdx.x * BN;

  // staging geometry (64B per LDS row of 32 bf16)
  const int ao0 = wid * 2048 + lane * 16;
  const int ar0 = ao0 >> 6,          ac0 = (ao0 & 63) >> 1;
  const int ar1 = (ao0 + 1024) >> 6, ac1 = ((ao0 + 1024) & 63) >> 1;
  const int bo0 = wid * (1024 * BISS) + lane * 16;
  const int br0 = bo0 >> 6,          bc0 = (bo0 & 63) >> 1;
  const int br1 = (bo0 + 1024) >> 6, bc1 = ((bo0 + 1024) & 63) >> 1;

  const u16t* Ab = A + (size_t)bm * K;
  const u16t* Bb = BT + (size_t)bn * K;

  f32x4 acc[MR][NR];
#pragma unroll
  for (int m = 0; m < MR; ++m)
#pragma unroll
    for (int n = 0; n < NR; ++n) acc[m][n] = (f32x4){0.f, 0.f, 0.f, 0.f};

  for (int k0 = 0; k0 < K; k0 += 32) {
    gload16(Ab + (size_t)ar0 * K + k0 + ac0, (char*)Al + wid * 2048);
    gload16(Ab + (size_t)ar1 * K + k0 + ac1, (char*)Al + wid * 2048 + 1024);
    gload16(Bb + (size_t)br0 * K + k0 + bc0, (char*)Bl + wid * 1024 * BISS);
    if (BISS == 2)
      gload16(Bb + (size_t)br1 * K + k0 + bc1, (char*)Bl + wid * 2048 + 1024);
    __syncthreads();                 // drains vmcnt before reads
    short8 af[MR], bf[NR];
#pragma unroll
    for (int m = 0; m < MR; ++m)
      af[m] = *(const short8*)&Al[(wr * WM + m * 16 + lr) * 32 + lq * 8];
#pragma unroll
    for (int n = 0; n < NR; ++n)
      bf[n] = *(const short8*)&Bl[(wc * 64 + n * 16 + lr) * 32 + lq * 8];
#pragma unroll
    for (int m = 0; m < MR; ++m)
#pragma unroll
      for (int n = 0; n < NR; ++n)
        acc[m][n] = __builtin_amdgcn_mfma_f32_16x16x32_bf16(af[m], bf[n], acc[m][n], 0, 0, 0);
    __syncthreads();                 // reads done before next-iter gload writes
  }

  if (EPI == 2) {                    // fused bias + GEGLU (permuted cols)
    const int Nh = N >> 1;
#pragma unroll
    for (int np = 0; np < NR / 2; ++np) {
      const int ca = bn + wc * 64 + np * 32 + lr;     // permuted-space col of a
      const float ba = bias[ca], bg = bias[ca + 16];
      const int uc = (bn >> 1) + wc * 32 + np * 16 + lr;
#pragma unroll
      for (int m = 0; m < MR; ++m) {
#pragma unroll
        for (int i = 0; i < 4; ++i) {
          const int row = bm + wr * WM + m * 16 + lq * 4 + i;
          const float a = acc[m][2 * np][i] + ba;
          const float g = acc[m][2 * np + 1][i] + bg;
          const float ge = 0.5f * g * (1.f + erff(g * 0.70710678118654752f));
          ((u16t*)C)[(size_t)row * Nh + uc] = f2b(a * ge);
        }
      }
    }
  } else {
#pragma unroll
    for (int n = 0; n < NR; ++n) {
      const int col = bn + wc * 64 + n * 16 + lr;
      const float bv = bias ? bias[col] : 0.f;
#pragma unroll
      for (int m = 0; m < MR; ++m) {
#pragma unroll
        for (int i = 0; i < 4; ++i) {
          const int row = bm + wr * WM + m * 16 + lq * 4 + i;
          float v = acc[m][n][i] + bv;
          if (EPI == 1) {
            v += res[(size_t)row * N + col];
            ((float*)C)[(size_t)row * N + col] = v;
          } else {
            ((u16t*)C)[(size_t)row * N + col] = f2b(v);
          }
        }
      }
    }
  }
}

// ---------------- MFMA attention (no per-tile barriers) --------------------
template<int NTOK>
__global__ __launch_bounds__(256) void attn_mfma(
    const u16t* __restrict__ qkv, float* __restrict__ share,
    u16t* __restrict__ outb) {
  __shared__ u16t VT[16][NTOK + 40];
  __shared__ u16t PB[4][16][40];     // per-wave P bounce tile
  const int t = threadIdx.x, lane = t & 63, wv = t >> 6;
  const int lr = lane & 15, lq = lane >> 4;
  const int bpb = NTOK / 64;
  const int bh = blockIdx.x / bpb, rg = blockIdx.x % bpb;
  const int b = bh >> 3, h = bh & 7;
  const u16t* qkvb = qkv + (size_t)b * NTOK * 384;

  for (int tok = t; tok < NTOK; tok += 256) {
    const u16t* vp = qkvb + (size_t)tok * 384 + 256 + h * 16;
    short8 v0 = *(const short8*)vp;
    short8 v1 = *(const short8*)(vp + 8);
#pragma unroll
    for (int d = 0; d < 8; ++d) {
      VT[d][tok]     = (u16t)v0[d];
      VT[d + 8][tok] = (u16t)v1[d];
    }
  }
  __syncthreads();

  const int i0 = rg * 64 + wv * 16;
  short8 qf = {0, 0, 0, 0, 0, 0, 0, 0};
  if (lq < 2)
    qf = *(const short8*)(qkvb + (size_t)(i0 + lr) * 384 + h * 16 + lq * 8);

  f32x4 oacc = {0.f, 0.f, 0.f, 0.f};
  f32x4 sacc = {0.f, 0.f, 0.f, 0.f};
  const f32x4 zero = {0.f, 0.f, 0.f, 0.f};
  float* shb = share + (size_t)bh * NTOK * NTOK;

  for (int t0 = 0; t0 < NTOK; t0 += 32) {
#pragma unroll
    for (int s2 = 0; s2 < 2; ++s2) {
      short8 kf = {0, 0, 0, 0, 0, 0, 0, 0};
      if (lq < 2)
        kf = *(const short8*)(qkvb + (size_t)(t0 + s2 * 16 + lr) * 384 + 128 + h * 16 + lq * 8);
      f32x4 e = __builtin_amdgcn_mfma_f32_16x16x32_bf16(qf, kf, zero, 0, 0, 0);
#pragma unroll
      for (int i = 0; i < 4; ++i) {
        const float ev = e[i] * 0.25f;
        shb[(size_t)(i0 + lq * 4 + i) * NTOK + t0 + s2 * 16 + lr] = ev;
        const float p = __expf(ev);
        sacc[i] += p;
        PB[wv][lq * 4 + i][s2 * 16 + lr] = f2b(p);
      }
    }
    // per-wave tile: DS pipe is in-order per wave; wait writes, pin order
    asm volatile("s_waitcnt lgkmcnt(0)" ::: "memory");
    __builtin_amdgcn_sched_barrier(0);
    short8 pa = *(const short8*)&PB[wv][lr][lq * 8];
    short8 vf = *(const short8*)&VT[lr][t0 + lq * 8];
    oacc = __builtin_amdgcn_mfma_f32_16x16x32_bf16(pa, vf, oacc, 0, 0, 0);
    __builtin_amdgcn_sched_barrier(0);   // keep next-iter PB writes after reads
  }
#pragma unroll
  for (int i = 0; i < 4; ++i) {
    float s = sacc[i];
    s += __shfl_xor(s, 1); s += __shfl_xor(s, 2);
    s += __shfl_xor(s, 4); s += __shfl_xor(s, 8);
    sacc[i] = s;
  }
#pragma unroll
  for (int i = 0; i < 4; ++i) {
    const float o = oacc[i] / sacc[i];
    outb[((size_t)(b * NTOK) + i0 + lq * 4 + i) * 128 + h * 16 + lr] = f2b(o);
  }
}

// ---------------- LayerNorm (input pre-summed), float4 vectorized ----------
template<int NT, bool B16>
__global__ __launch_bounds__(NT) void ln_vec(
    const float* __restrict__ xin, const float* __restrict__ g,
    const float* __restrict__ be, float* __restrict__ y32,
    u16t* __restrict__ y16, int D) {
  const int row = blockIdx.x, t = threadIdx.x;
  const int lane = t & 63;
  const float4 x = ((const float4*)xin)[(size_t)row * (D >> 2) + t];
  float s = x.x + x.y + x.z + x.w;
  float s2 = x.x * x.x + x.y * x.y + x.z * x.z + x.w * x.w;
#pragma unroll
  for (int off = 32; off; off >>= 1) {
    s  += __shfl_xor(s, off);
    s2 += __shfl_xor(s2, off);
  }
  if (NT == 128) {
    __shared__ float a1[2], a2[2];
    const int wv = t >> 6;
    if (lane == 0) { a1[wv] = s; a2[wv] = s2; }
    __syncthreads();
    s = a1[0] + a1[1]; s2 = a2[0] + a2[1];
  }
  const float mean = s / D;
  const float var  = s2 / D - mean * mean;
  const float rstd = rsqrtf(var + 1e-5f);
  const float4 gv = ((const float4*)g)[t];
  const float4 bv = ((const float4*)be)[t];
  float4 y;
  y.x = (x.x - mean) * rstd * gv.x + bv.x;
  y.y = (x.y - mean) * rstd * gv.y + bv.y;
  y.z = (x.z - mean) * rstd * gv.z + bv.z;
  y.w = (x.w - mean) * rstd * gv.w + bv.w;
  ((float4*)y32)[(size_t)row * (D >> 2) + t] = y;
  if (B16) {
    bf16x4 p;
    p[0] = (short)f2b(y.x); p[1] = (short)f2b(y.y);
    p[2] = (short)f2b(y.z); p[3] = (short)f2b(y.w);
    *(bf16x4*)&y16[(size_t)row * D + t * 4] = p;
  }
}

// ---------------- batched transpose [B][R][C]->[B][C][R], opt bf16 twin ----
template<bool BF16OUT>
__global__ void transp(const float* __restrict__ in, float* __restrict__ out32,
                       u16t* __restrict__ out16, int R, int C) {
  __shared__ float tile[32][33];
  const int b = blockIdx.z;
  const int r0 = blockIdx.y << 5, c0 = blockIdx.x << 5;
  const float* inb = in + (size_t)b * R * C;
  const int tx = threadIdx.x, ty = threadIdx.y;
#pragma unroll
  for (int dy = 0; dy < 32; dy += 8)
    tile[ty + dy][tx] = inb[(size_t)(r0 + ty + dy) * C + c0 + tx];
  __syncthreads();
#pragma unroll
  for (int dy = 0; dy < 32; dy += 8) {
    const float v = tile[tx][ty + dy];
    const size_t idx = (size_t)b * R * C + (size_t)(c0 + ty + dy) * R + r0 + tx;
    out32[idx] = v;
    if (BF16OUT) out16[idx] = f2b(v);
  }
}

// ---------------- one-shot prep: x->bf16, 8 weight T's, 2 bias perms -------
__global__ __launch_bounds__(256) void prep_all(
    const float* __restrict__ x0, u16t* __restrict__ x16,
    const float* __restrict__ wqkv1, u16t* __restrict__ tqkv1,
    const float* __restrict__ wo1,   u16t* __restrict__ two1,
    const float* __restrict__ ff1w1, u16t* __restrict__ tff1a,
    const float* __restrict__ ff1w2, u16t* __restrict__ tff1b,
    const float* __restrict__ wqkv2, u16t* __restrict__ tqkv2,
    const float* __restrict__ wo2,   u16t* __restrict__ two2,
    const float* __restrict__ ff2w1, u16t* __restrict__ tff2a,
    const float* __restrict__ ff2w2, u16t* __restrict__ tff2b,
    const float* __restrict__ ff1b1, float* __restrict__ bp1,
    const float* __restrict__ ff2b1, float* __restrict__ bp2) {
  __shared__ float tile[32][33];
  const int b = blockIdx.x, t = threadIdx.x;
  const int tx = t & 31, ty = t >> 5;
  const float* src; u16t* dst;
  int K, N, bxd, blk, halfN = 0; bool perm = false;
  if (b < 1024) {                        // x -> bf16 (8 elems/thread)
    const float* p = x0 + (size_t)(b * 256 + t) * 8;
    short8 v;
#pragma unroll
    for (int j = 0; j < 8; ++j) v[j] = (short)f2b(p[j]);
    *(short8*)(x16 + (size_t)(b * 256 + t) * 8) = v;
    return;
  } else if (b < 1120) { src = wqkv1; dst = tqkv1; K = 256;  N = 384;  bxd = 12;  blk = b - 1024; }
  else if (b < 1152)   { src = wo1;   dst = two1;  K = 128;  N = 256;  bxd = 8;   blk = b - 1120; }
  else if (b < 1664)   { src = ff1w1; dst = tff1a; K = 256;  N = 2048; bxd = 64;  blk = b - 1152; perm = true; halfN = 1024; }
  else if (b < 1920)   { src = ff1w2; dst = tff1b; K = 1024; N = 256;  bxd = 8;   blk = b - 1664; }
  else if (b < 2112)   { src = wqkv2; dst = tqkv2; K = 512;  N = 384;  bxd = 12;  blk = b - 1920; }
  else if (b < 2176)   { src = wo2;   dst = two2;  K = 128;  N = 512;  bxd = 16;  blk = b - 2112; }
  else if (b < 4224)   { src = ff2w1; dst = tff2a; K = 512;  N = 4096; bxd = 128; blk = b - 2176; perm = true; halfN = 2048; }
  else if (b < 5248)   { src = ff2w2; dst = tff2b; K = 2048; N = 512;  bxd = 16;  blk = b - 4224; }
  else if (b < 5256) { const int n = (b - 5248) * 256 + t; bp1[n] = ff1b1[origcol(n, 1024)]; return; }
  else               { const int n = (b - 5256) * 256 + t; bp2[n] = ff2b1[origcol(n, 2048)]; return; }

  const int bx = blk % bxd, by = blk / bxd;
  const int n0 = bx * 32, k0 = by * 32;
  const int nn = n0 + tx;
  const int no = perm ? origcol(nn, halfN) : nn;
#pragma unroll
  for (int dy = 0; dy < 32; dy += 8)
    tile[ty + dy][tx] = src[(size_t)(k0 + ty + dy) * N + no];
  __syncthreads();
#pragma unroll
  for (int dy = 0; dy < 32; dy += 8)
    dst[(size_t)(n0 + ty + dy) * K + k0 + tx] = f2b(tile[tx][ty + dy]);
}

// ---------------------------------------------------------------------------
extern "C" void kernel_launch(void* const* d_in, const int* in_sizes, int n_in,
                              void* d_out, int out_size, void* d_ws, size_t ws_size,
                              hipStream_t stream) {
  (void)in_sizes; (void)n_in; (void)out_size; (void)ws_size;
  const float* x0    = (const float*)d_in[0];
  const float* wqkv1 = (const float*)d_in[1];
  const float* wo1   = (const float*)d_in[2];
  const float* bo1   = (const float*)d_in[3];
  const float* ff1w1 = (const float*)d_in[4];
  const float* ff1b1 = (const float*)d_in[5];
  const float* ff1w2 = (const float*)d_in[6];
  const float* ff1b2 = (const float*)d_in[7];
  const float* wqkv2 = (const float*)d_in[8];
  const float* wo2   = (const float*)d_in[9];
  const float* bo2   = (const float*)d_in[10];
  const float* ff2w1 = (const float*)d_in[11];
  const float* ff2b1 = (const float*)d_in[12];
  const float* ff2w2 = (const float*)d_in[13];
  const float* ff2b2 = (const float*)d_in[14];
  const float* ln1g  = (const float*)d_in[15];
  const float* ln1b  = (const float*)d_in[16];
  const float* ln2g  = (const float*)d_in[17];
  const float* ln2b  = (const float*)d_in[18];
  const float* ln3g  = (const float*)d_in[19];
  const float* ln3b  = (const float*)d_in[20];
  const float* ln4g  = (const float*)d_in[21];
  const float* ln4b  = (const float*)d_in[22];

  float* out_x  = (float*)d_out;
  float* share1 = out_x + (size_t)2097152;
  float* share2 = share1 + (size_t)33554432;

  size_t off = 0;
  auto carve = [&](size_t bytes) -> void* {
    void* p = (char*)d_ws + off;
    off += (bytes + 255) & ~(size_t)255;
    return p;
  };
  u16t*  x16    = (u16t*)carve((size_t)8192 * 256 * 2);
  u16t*  qkv16  = (u16t*)carve((size_t)8192 * 384 * 2);
  u16t*  attn16 = (u16t*)carve((size_t)8192 * 128 * 2);
  float* sumb   = (float*)carve((size_t)8192 * 256 * 4);
  float* xa32   = (float*)carve((size_t)8192 * 256 * 4);
  u16t*  xa16   = (u16t*)carve((size_t)8192 * 256 * 2);
  float* xb32   = (float*)carve((size_t)8192 * 256 * 4);
  float* xt32   = (float*)carve((size_t)8192 * 256 * 4);
  u16t*  xt16   = (u16t*)carve((size_t)8192 * 256 * 2);
  float* xc32   = (float*)carve((size_t)8192 * 256 * 4);
  u16t*  xc16   = (u16t*)carve((size_t)8192 * 256 * 2);
  float* xd32   = (float*)carve((size_t)8192 * 256 * 4);
  u16t*  ubuf   = (u16t*)carve((size_t)4096 * 2048 * 2);
  u16t*  tqkv1  = (u16t*)carve((size_t)384 * 256 * 2);
  u16t*  two1   = (u16t*)carve((size_t)256 * 128 * 2);
  u16t*  tff1a  = (u16t*)carve((size_t)2048 * 256 * 2);
  u16t*  tff1b  = (u16t*)carve((size_t)256 * 1024 * 2);
  u16t*  tqkv2  = (u16t*)carve((size_t)384 * 512 * 2);
  u16t*  two2   = (u16t*)carve((size_t)512 * 128 * 2);
  u16t*  tff2a  = (u16t*)carve((size_t)4096 * 512 * 2);
  u16t*  tff2b  = (u16t*)carve((size_t)512 * 2048 * 2);
  float* bp1    = (float*)carve((size_t)2048 * 4);
  float* bp2    = (float*)carve((size_t)4096 * 4);

  const dim3 tb(32, 8);

  prep_all<<<5272, 256, 0, stream>>>(x0, x16, wqkv1, tqkv1, wo1, two1,
      ff1w1, tff1a, ff1w2, tff1b, wqkv2, tqkv2, wo2, two2,
      ff2w1, tff2a, ff2w2, tff2b, ff1b1, bp1, ff2b1, bp2);

  // ---- stage 1 (tokens=512, feat=256) ----
  mgemm<64, 0><<<dim3(6, 64), 256, 0, stream>>>(x16, tqkv1, nullptr, nullptr, qkv16, 8192, 384, 256);
  attn_mfma<512><<<1024, 256, 0, stream>>>(qkv16, share1, attn16);
  mgemm<64, 1><<<dim3(4, 64), 256, 0, stream>>>(attn16, two1, bo1, x0, sumb, 8192, 256, 128);
  ln_vec<64, true><<<8192, 64, 0, stream>>>(sumb, ln1g, ln1b, xa32, xa16, 256);
  mgemm<128, 2><<<dim3(16, 64), 256, 0, stream>>>(xa16, tff1a, bp1, nullptr, ubuf, 8192, 2048, 256);
  mgemm<64, 1><<<dim3(4, 64), 256, 0, stream>>>(ubuf, tff1b, ff1b2, xa32, sumb, 8192, 256, 1024);
  ln_vec<64, false><<<8192, 64, 0, stream>>>(sumb, ln2g, ln2b, xb32, nullptr, 256);

  // ---- transpose to [B,256,512] ----
  transp<true><<<dim3(8, 16, 16), tb, 0, stream>>>(xb32, xt32, xt16, 512, 256);

  // ---- stage 2 (tokens=256, feat=512) ----
  mgemm<64, 0><<<dim3(6, 32), 256, 0, stream>>>(xt16, tqkv2, nullptr, nullptr, qkv16, 4096, 384, 512);
  attn_mfma<256><<<512, 256, 0, stream>>>(qkv16, share2, attn16);
  mgemm<64, 1><<<dim3(8, 32), 256, 0, stream>>>(attn16, two2, bo2, xt32, sumb, 4096, 512, 128);
  ln_vec<128, true><<<4096, 128, 0, stream>>>(sumb, ln3g, ln3b, xc32, xc16, 512);
  mgemm<128, 2><<<dim3(32, 32), 256, 0, stream>>>(xc16, tff2a, bp2, nullptr, ubuf, 4096, 4096, 512);
  mgemm<64, 1><<<dim3(8, 32), 256, 0, stream>>>(ubuf, tff2b, ff2b2, xc32, sumb, 4096, 512, 2048);
  ln_vec<128, false><<<4096, 128, 0, stream>>>(sumb, ln4g, ln4b, xd32, nullptr, 512);

  // ---- transpose back -> out ----
  transp<false><<<dim3(16, 8, 16), tb, 0, stream>>>(xd32, out_x, nullptr, 256, 512);
}